// Round 1
// 12226.212 us; speedup vs baseline: 1.1122x; 1.1122x over previous
//
#include <hip/hip_runtime.h>

#define B_ 64
#define S_ 512
#define D_ 1024
#define H_ 1024
#define NBLK 256
#define NT 256

typedef __bf16 v8bf __attribute__((ext_vector_type(8)));
typedef float v4f __attribute__((ext_vector_type(4)));
typedef float f32x4 __attribute__((ext_vector_type(4)));

// Convert 8 consecutive f32 (32B, two float4 loads) to a bf16x8 fragment.
__device__ inline v8bf cvt8(const float* p) {
  f32x4 a = *(const f32x4*)p;
  f32x4 b = *(const f32x4*)(p + 4);
  v8bf r;
  r[0] = (__bf16)a[0]; r[1] = (__bf16)a[1]; r[2] = (__bf16)a[2]; r[3] = (__bf16)a[3];
  r[4] = (__bf16)b[0]; r[5] = (__bf16)b[1]; r[6] = (__bf16)b[2]; r[7] = (__bf16)b[3];
  return r;
}

// Persistent LSTM kernel. Inputs f32, OUTPUT f32 (reference is all-f32 JAX).
// Grid: 256 blocks x 256 threads. Block nb owns output columns [nb*4, nb*4+4)
// across all 4 gates (16 n-values). Weights for those 16 rows of [Wx;Wh]
// (16 x 2048, cvt f32->bf16 = 64KB) staged in LDS once, XOR-swizzled in 16B
// chunks so B-fragment ds_read_b128 is 2-way-bank-aliased (free on gfx950).
// Per step: g = [x_t, h_t] @ W^T via mfma_f32_16x16x32_bf16 (M=64 split
// across 4 waves, N=16, K=2048). x-part (K<1024) runs before the grid wait to
// hide barrier latency. h double-buffered (bf16) in ws; c in registers.
//
// BARRIER (new this round): the old single atomic counter serialized 256
// contended RMWs on one LLC line per step (~25us/step -- matches the measured
// 26.5us/step with MfmaUtil=1.6%). Replaced by distributed arrival flags:
// block i stores flags[i]=t+1 (release-fenced, no RMW); thread j of every
// block polls flags[j] (256 threads <-> 256 blocks, coalesced), then
// __syncthreads + per-wave acquire fence. No shared-line contention.
__global__ __launch_bounds__(NT, 1)
void lstm_persist(const float* __restrict__ x,    // (B,S,D) f32
                  const float* __restrict__ Wx,   // (4,H,D) f32
                  const float* __restrict__ Wh,   // (4,H,H) f32
                  const float* __restrict__ bias, // (4,H)   f32
                  float* __restrict__ out,        // (B,S,H) ++ (B,H) ++ (B,H), f32
                  __bf16* __restrict__ hbuf,      // (2,B,H) bf16 double buffer
                  unsigned* __restrict__ flags)   // [NBLK] per-block step flags
{
  __shared__ v8bf wlds[16 * 256];  // [nl][kc ^ (nl&7)] 16B chunks, 64KB

  const int tid  = threadIdx.x;
  const int nb   = blockIdx.x;
  const int w    = tid >> 6;   // wave 0..3
  const int l    = tid & 63;
  const int lm   = l & 15;     // MFMA row (A) / col (B,D) lane index
  const int quad = l >> 4;     // MFMA k-quad
  const int sw   = lm & 7;     // LDS swizzle key

  // ---- stage weights into LDS (once), f32 -> bf16 ----
  for (int i = tid; i < 16 * 256; i += NT) {
    const int nl  = i >> 8;          // 0..15: gate g = nl>>2, local col = nl&3
    const int kc  = i & 255;         // 8-elt chunk index along K (k = kc*8)
    const int g   = nl >> 2;
    const int col = (nb << 2) + (nl & 3);
    const int k   = kc << 3;
    const float* src = (k < D_)
        ? (Wx + ((size_t)(g * H_ + col) * D_ + k))
        : (Wh + ((size_t)(g * H_ + col) * H_ + (k - D_)));
    wlds[(nl << 8) + (kc ^ (nl & 7))] = cvt8(src);
  }

  const int myb   = (w << 4) + lm;      // batch row this lane owns
  const int mycol = (nb << 2) + quad;   // H-column this lane owns (elementwise)
  float bv[4];
  #pragma unroll
  for (int g = 0; g < 4; ++g) bv[g] = bias[g * H_ + mycol];

  float c_reg = 0.f;  // cell state for (myb, mycol), lives in a register

  __syncthreads();

  for (int t = 0; t < S_; ++t) {
    v4f acc0 = {0.f, 0.f, 0.f, 0.f};
    v4f acc1 = {0.f, 0.f, 0.f, 0.f};

    // ---- x part (K = 0..1023): no dependence on h, runs before the wait ----
    const float* xrow = x + ((size_t)(myb * S_ + t)) * D_ + (quad << 3);
    #pragma unroll 4
    for (int qq = 0; qq < 16; ++qq) {
      const int q0 = qq * 2, q1 = qq * 2 + 1;
      v8bf a0 = cvt8(xrow + (q0 << 5));
      v8bf b0 = wlds[(lm << 8) + (((q0 << 2) + quad) ^ sw)];
      acc0 = __builtin_amdgcn_mfma_f32_16x16x32_bf16(a0, b0, acc0, 0, 0, 0);
      v8bf a1 = cvt8(xrow + (q1 << 5));
      v8bf b1 = wlds[(lm << 8) + (((q1 << 2) + quad) ^ sw)];
      acc1 = __builtin_amdgcn_mfma_f32_16x16x32_bf16(a1, b1, acc1, 0, 0, 0);
    }

    // ---- wait for all h_t writes (distributed flags), then h part ----
    if (t > 0) {
      // thread j polls block j's flag: no contention, coalesced 256B/wave.
      while (__hip_atomic_load(&flags[tid], __ATOMIC_RELAXED,
                               __HIP_MEMORY_SCOPE_AGENT) < (unsigned)t) {
        __builtin_amdgcn_s_sleep(1);
      }
      __syncthreads();  // all 256 flags observed across the block
      // acquire: invalidate L1/L2 so h reads see other XCDs' writes.
      __builtin_amdgcn_fence(__ATOMIC_ACQUIRE, "agent");

      const __bf16* hrow = hbuf + ((t & 1) ? (size_t)(B_ * H_) : 0)
                                + (size_t)myb * H_ + (quad << 3);
      #pragma unroll 4
      for (int qq = 0; qq < 16; ++qq) {
        const int q0 = qq * 2, q1 = qq * 2 + 1;
        v8bf a0 = *(const v8bf*)(hrow + (q0 << 5));
        v8bf b0 = wlds[(lm << 8) + ((128 + (q0 << 2) + quad) ^ sw)];
        acc0 = __builtin_amdgcn_mfma_f32_16x16x32_bf16(a0, b0, acc0, 0, 0, 0);
        v8bf a1 = *(const v8bf*)(hrow + (q1 << 5));
        v8bf b1 = wlds[(lm << 8) + ((128 + (q1 << 2) + quad) ^ sw)];
        acc1 = __builtin_amdgcn_mfma_f32_16x16x32_bf16(a1, b1, acc1, 0, 0, 0);
      }
    }

    v4f acc = acc0 + acc1;

    // ---- gate exchange: D layout row m=quad*4+r (batch), col n=lm.
    // Dest lane (b=16w+lm, c=quad) needs cols {g*4+quad} at row lm. ----
    float gv[4];
    const int rsel = lm & 3;
    #pragma unroll
    for (int g = 0; g < 4; ++g) {
      const int srcl = ((lm >> 2) << 4) + (g << 2) + quad;
      float t0 = __shfl(acc[0], srcl, 64);
      float t1 = __shfl(acc[1], srcl, 64);
      float t2 = __shfl(acc[2], srcl, 64);
      float t3 = __shfl(acc[3], srcl, 64);
      gv[g] = (rsel == 0 ? t0 : rsel == 1 ? t1 : rsel == 2 ? t2 : t3) + bv[g];
    }

    // ---- LSTM pointwise (fp32) ----
    const float it = 1.f / (1.f + __expf(-gv[0]));
    const float ft = 1.f / (1.f + __expf(-gv[1]));
    const float ot = 1.f / (1.f + __expf(-gv[2]));
    const float ch = 1.f - 2.f / (__expf(2.f * gv[3]) + 1.f);  // tanh
    c_reg = ft * c_reg + it * ch;
    const float hn = ot * (1.f - 2.f / (__expf(2.f * c_reg) + 1.f));

    // bf16 feedback first: it is what the release/flag protects.
    hbuf[(((t + 1) & 1) ? (size_t)(B_ * H_) : 0)
         + (size_t)myb * H_ + mycol] = (__bf16)hn;

    __syncthreads();  // drains every wave's hbuf stores (vmcnt) before release
    if (tid == 0) {
      // release: write back L2 so h is visible device-wide, then arrive.
      __builtin_amdgcn_fence(__ATOMIC_RELEASE, "agent");
      __hip_atomic_store(&flags[nb], (unsigned)(t + 1), __ATOMIC_RELAXED,
                         __HIP_MEMORY_SCOPE_AGENT);
    }

    // ---- streamed outputs: never re-read; nontemporal + after the release
    // so they stay off the critical path and out of the wbl2 drain. ----
    __builtin_nontemporal_store(hn, &out[((size_t)(myb * S_ + t)) * H_ + mycol]);
    if (t == S_ - 1) {
      __builtin_nontemporal_store(
          hn, &out[(size_t)B_ * S_ * H_ + (size_t)myb * H_ + mycol]);   // h_last
      __builtin_nontemporal_store(
          c_reg, &out[(size_t)B_ * S_ * H_ + (size_t)(B_ * H_)
                      + (size_t)myb * H_ + mycol]);                      // c_last
    }
  }
}

extern "C" void kernel_launch(void* const* d_in, const int* in_sizes, int n_in,
                              void* d_out, int out_size, void* d_ws, size_t ws_size,
                              hipStream_t stream) {
  const float* x    = (const float*)d_in[0];
  const float* Wx   = (const float*)d_in[1];
  const float* Wh   = (const float*)d_in[2];
  const float* bias = (const float*)d_in[3];
  float* out = (float*)d_out;

  unsigned* flags = (unsigned*)d_ws;                 // NBLK*4 = 1KB region
  __bf16*   hbuf  = (__bf16*)((char*)d_ws + 4096);   // 2*B*H bf16 = 256KB

  // ws is poisoned 0xAA before every timed launch: zero the flag region.
  hipMemsetAsync(d_ws, 0, 4096, stream);

  lstm_persist<<<dim3(NBLK), dim3(NT), 0, stream>>>(x, Wx, Wh, bias, out, hbuf,
                                                    flags);
}

// Round 2
// 11954.295 us; speedup vs baseline: 1.1375x; 1.0227x over previous
//
#include <hip/hip_runtime.h>

#define B_ 64
#define S_ 512
#define D_ 1024
#define H_ 1024
#define NBLK 256
#define NT 256

typedef __bf16 v8bf __attribute__((ext_vector_type(8)));
typedef float v4f __attribute__((ext_vector_type(4)));
typedef float f32x4 __attribute__((ext_vector_type(4)));

// Convert 8 consecutive f32 (32B, two float4 loads) to a bf16x8 fragment.
__device__ inline v8bf cvt8(const float* p) {
  f32x4 a = *(const f32x4*)p;
  f32x4 b = *(const f32x4*)(p + 4);
  v8bf r;
  r[0] = (__bf16)a[0]; r[1] = (__bf16)a[1]; r[2] = (__bf16)a[2]; r[3] = (__bf16)a[3];
  r[4] = (__bf16)b[0]; r[5] = (__bf16)b[1]; r[6] = (__bf16)b[2]; r[7] = (__bf16)b[3];
  return r;
}

// Load one 16B h-fragment with agent-scope (sc1) loads: bypasses the
// non-coherent per-XCD L2 and reads the LLC directly. Required both for
// correctness (double-buffered addresses recur every 2 steps; a plain load
// could hit a stale L2 line) and to avoid any buffer_inv bulk fence.
__device__ inline v8bf load16_llc(const unsigned* p) {
  union { unsigned u[4]; v8bf v; } r;
  r.u[0] = __hip_atomic_load(p + 0, __ATOMIC_RELAXED, __HIP_MEMORY_SCOPE_AGENT);
  r.u[1] = __hip_atomic_load(p + 1, __ATOMIC_RELAXED, __HIP_MEMORY_SCOPE_AGENT);
  r.u[2] = __hip_atomic_load(p + 2, __ATOMIC_RELAXED, __HIP_MEMORY_SCOPE_AGENT);
  r.u[3] = __hip_atomic_load(p + 3, __ATOMIC_RELAXED, __HIP_MEMORY_SCOPE_AGENT);
  return r.v;
}

// Persistent LSTM kernel. Inputs f32, OUTPUT f32 (reference is all-f32 JAX).
// Grid: 256 blocks x 256 threads. Block nb owns output columns [nb*4, nb*4+4)
// across all 4 gates (16 n-values). Weights for those 16 rows of [Wx;Wh]
// (16 x 2048, cvt f32->bf16 = 64KB) staged in LDS once, XOR-swizzled in 16B
// chunks so B-fragment ds_read_b128 is 2-way-bank-aliased (free on gfx950).
// Per step: g = [x_t, h_t] @ W^T via mfma_f32_16x16x32_bf16 (M=64 split
// across 4 waves, N=16, K=2048). x-part (K<1024) runs before the grid wait to
// hide barrier latency. h double-buffered (bf16) in ws; c in registers.
//
// COHERENCE (new this round): rounds 0-1 used agent-scope FENCES per step
// (buffer_inv + buffer_wbl2 = full 4MiB-L2 tag walks, x32 blocks/XCD/step)
// -- priced at ~20us/step, matching the measured stall with every pipe <4%
// busy. Replaced by instruction-granularity coherence on the h traffic only
// (the RCCL fine-grain signaling pattern): h stores/loads are agent-scope
// (sc1) write-through/LLC-direct ops; __syncthreads' implicit vmcnt(0) drain
// orders h stores before the (relaxed, sc1) flag store. No bulk fences.
__global__ __launch_bounds__(NT, 1)
void lstm_persist(const float* __restrict__ x,    // (B,S,D) f32
                  const float* __restrict__ Wx,   // (4,H,D) f32
                  const float* __restrict__ Wh,   // (4,H,H) f32
                  const float* __restrict__ bias, // (4,H)   f32
                  float* __restrict__ out,        // (B,S,H) ++ (B,H) ++ (B,H), f32
                  __bf16* __restrict__ hbuf,      // (2,B,H) bf16 double buffer
                  unsigned* __restrict__ flags)   // [NBLK] per-block step flags
{
  __shared__ v8bf wlds[16 * 256];  // [nl][kc ^ (nl&7)] 16B chunks, 64KB

  const int tid  = threadIdx.x;
  const int nb   = blockIdx.x;
  const int w    = tid >> 6;   // wave 0..3
  const int l    = tid & 63;
  const int lm   = l & 15;     // MFMA row (A) / col (B,D) lane index
  const int quad = l >> 4;     // MFMA k-quad
  const int sw   = lm & 7;     // LDS swizzle key

  // ---- stage weights into LDS (once), f32 -> bf16 ----
  for (int i = tid; i < 16 * 256; i += NT) {
    const int nl  = i >> 8;          // 0..15: gate g = nl>>2, local col = nl&3
    const int kc  = i & 255;         // 8-elt chunk index along K (k = kc*8)
    const int g   = nl >> 2;
    const int col = (nb << 2) + (nl & 3);
    const int k   = kc << 3;
    const float* src = (k < D_)
        ? (Wx + ((size_t)(g * H_ + col) * D_ + k))
        : (Wh + ((size_t)(g * H_ + col) * H_ + (k - D_)));
    wlds[(nl << 8) + (kc ^ (nl & 7))] = cvt8(src);
  }

  const int myb   = (w << 4) + lm;      // batch row this lane owns
  const int mycol = (nb << 2) + quad;   // H-column this lane owns (elementwise)
  float bv[4];
  #pragma unroll
  for (int g = 0; g < 4; ++g) bv[g] = bias[g * H_ + mycol];

  float c_reg = 0.f;  // cell state for (myb, mycol), lives in a register

  __syncthreads();

  for (int t = 0; t < S_; ++t) {
    v4f acc0 = {0.f, 0.f, 0.f, 0.f};
    v4f acc1 = {0.f, 0.f, 0.f, 0.f};

    // ---- x part (K = 0..1023): no dependence on h, runs before the wait ----
    const float* xrow = x + ((size_t)(myb * S_ + t)) * D_ + (quad << 3);
    #pragma unroll 4
    for (int qq = 0; qq < 16; ++qq) {
      const int q0 = qq * 2, q1 = qq * 2 + 1;
      v8bf a0 = cvt8(xrow + (q0 << 5));
      v8bf b0 = wlds[(lm << 8) + (((q0 << 2) + quad) ^ sw)];
      acc0 = __builtin_amdgcn_mfma_f32_16x16x32_bf16(a0, b0, acc0, 0, 0, 0);
      v8bf a1 = cvt8(xrow + (q1 << 5));
      v8bf b1 = wlds[(lm << 8) + (((q1 << 2) + quad) ^ sw)];
      acc1 = __builtin_amdgcn_mfma_f32_16x16x32_bf16(a1, b1, acc1, 0, 0, 0);
    }

    // ---- wait for all h_t writes (distributed flags), then h part ----
    if (t > 0) {
      // thread j polls block j's flag: no contention, coalesced, sc1 (LLC).
      while (__hip_atomic_load(&flags[tid], __ATOMIC_RELAXED,
                               __HIP_MEMORY_SCOPE_AGENT) < (unsigned)t) {
        __builtin_amdgcn_s_sleep(1);
      }
      __syncthreads();  // all 256 flags observed; orders h loads after polls

      // h fragments: agent-scope dword loads straight from LLC (no fence).
      const unsigned* hrow =
          (const unsigned*)(hbuf + ((t & 1) ? (size_t)(B_ * H_) : 0)
                            + (size_t)myb * H_) + (quad << 2);
      #pragma unroll 4
      for (int qq = 0; qq < 16; ++qq) {
        const int q0 = qq * 2, q1 = qq * 2 + 1;
        v8bf a0 = load16_llc(hrow + (q0 << 4));
        v8bf b0 = wlds[(lm << 8) + ((128 + (q0 << 2) + quad) ^ sw)];
        acc0 = __builtin_amdgcn_mfma_f32_16x16x32_bf16(a0, b0, acc0, 0, 0, 0);
        v8bf a1 = load16_llc(hrow + (q1 << 4));
        v8bf b1 = wlds[(lm << 8) + ((128 + (q1 << 2) + quad) ^ sw)];
        acc1 = __builtin_amdgcn_mfma_f32_16x16x32_bf16(a1, b1, acc1, 0, 0, 0);
      }
    }

    v4f acc = acc0 + acc1;

    // ---- gate exchange: D layout row m=quad*4+r (batch), col n=lm.
    // Dest lane (b=16w+lm, c=quad) needs cols {g*4+quad} at row lm. ----
    float gv[4];
    const int rsel = lm & 3;
    #pragma unroll
    for (int g = 0; g < 4; ++g) {
      const int srcl = ((lm >> 2) << 4) + (g << 2) + quad;
      float t0 = __shfl(acc[0], srcl, 64);
      float t1 = __shfl(acc[1], srcl, 64);
      float t2 = __shfl(acc[2], srcl, 64);
      float t3 = __shfl(acc[3], srcl, 64);
      gv[g] = (rsel == 0 ? t0 : rsel == 1 ? t1 : rsel == 2 ? t2 : t3) + bv[g];
    }

    // ---- LSTM pointwise (fp32) ----
    const float it = 1.f / (1.f + __expf(-gv[0]));
    const float ft = 1.f / (1.f + __expf(-gv[1]));
    const float ot = 1.f / (1.f + __expf(-gv[2]));
    const float ch = 1.f - 2.f / (__expf(2.f * gv[3]) + 1.f);  // tanh
    c_reg = ft * c_reg + it * ch;
    const float hn = ot * (1.f - 2.f / (__expf(2.f * c_reg) + 1.f));

    // bf16 feedback: agent-scope (sc1) write-through store -> LLC. This is
    // what the flag release protects; no wbl2 fence needed because sc1
    // stores ack vmcnt at the LLC and __syncthreads drains vmcnt(0).
    {
      union { __bf16 b; unsigned short s; } hb;
      hb.b = (__bf16)hn;
      __hip_atomic_store(
          (unsigned short*)(hbuf + (((t + 1) & 1) ? (size_t)(B_ * H_) : 0)
                            + (size_t)myb * H_ + mycol),
          hb.s, __ATOMIC_RELAXED, __HIP_MEMORY_SCOPE_AGENT);
    }

    __syncthreads();  // implicit s_waitcnt vmcnt(0): all h stores are at LLC
    if (tid == 0) {
      __hip_atomic_store(&flags[nb], (unsigned)(t + 1), __ATOMIC_RELAXED,
                         __HIP_MEMORY_SCOPE_AGENT);
    }

    // ---- streamed outputs: never re-read; nontemporal + after the release
    // so they stay off the critical path. ----
    __builtin_nontemporal_store(hn, &out[((size_t)(myb * S_ + t)) * H_ + mycol]);
    if (t == S_ - 1) {
      __builtin_nontemporal_store(
          hn, &out[(size_t)B_ * S_ * H_ + (size_t)myb * H_ + mycol]);   // h_last
      __builtin_nontemporal_store(
          c_reg, &out[(size_t)B_ * S_ * H_ + (size_t)(B_ * H_)
                      + (size_t)myb * H_ + mycol]);                      // c_last
    }
  }
}

extern "C" void kernel_launch(void* const* d_in, const int* in_sizes, int n_in,
                              void* d_out, int out_size, void* d_ws, size_t ws_size,
                              hipStream_t stream) {
  const float* x    = (const float*)d_in[0];
  const float* Wx   = (const float*)d_in[1];
  const float* Wh   = (const float*)d_in[2];
  const float* bias = (const float*)d_in[3];
  float* out = (float*)d_out;

  unsigned* flags = (unsigned*)d_ws;                 // NBLK*4 = 1KB region
  __bf16*   hbuf  = (__bf16*)((char*)d_ws + 4096);   // 2*B*H bf16 = 256KB

  // ws is poisoned 0xAA before every timed launch: zero the flag region.
  hipMemsetAsync(d_ws, 0, 4096, stream);

  lstm_persist<<<dim3(NBLK), dim3(NT), 0, stream>>>(x, Wx, Wh, bias, out, hbuf,
                                                    flags);
}